// Round 1
// baseline (188.469 us; speedup 1.0000x reference)
//
#include <hip/hip_runtime.h>
#include <hip/hip_bf16.h>

// Problem constants (fixed by the reference: B=64, C=8, V=50000, H=128)
constexpr int Bn = 64;
constexpr int Cn = 8;
constexpr int Vn = 50000;
constexpr int Hn = 128;

// ---------------------------------------------------------------------------
// Kernel 1: s[v] = sum_h W_ctx[v,h].  One 64-lane wave per row; each lane
// reads a float2 (64*8B = 512B contiguous per row), shuffle-reduce.
// ---------------------------------------------------------------------------
__global__ __launch_bounds__(256) void rowsum_kernel(
    const float* __restrict__ Wctx, float* __restrict__ s) {
    int gwave = (blockIdx.x * blockDim.x + threadIdx.x) >> 6;
    int lane  = threadIdx.x & 63;
    if (gwave >= Vn) return;
    const float2* row = (const float2*)(Wctx + (size_t)gwave * Hn);
    float2 v = row[lane];            // H=128 -> 64 lanes x 2 floats
    float sum = v.x + v.y;
    #pragma unroll
    for (int off = 32; off > 0; off >>= 1)
        sum += __shfl_down(sum, off, 64);
    if (lane == 0) s[gwave] = sum;
}

// ---------------------------------------------------------------------------
// Kernel 2: latent[r] = dot(x[r, :], s[:]) for r in [0, B*C).
// One block of 1024 threads per row; float4 loads; wave + block reduce.
// 512 blocks = 2 blocks/CU, 32 waves/CU -> full occupancy for BW hiding.
// ---------------------------------------------------------------------------
__global__ __launch_bounds__(1024) void dot_kernel(
    const float* __restrict__ x, const float* __restrict__ s,
    float* __restrict__ latent) {
    constexpr int n4 = Vn / 4;  // 12500, V % 4 == 0
    const float4* xr = (const float4*)(x + (size_t)blockIdx.x * Vn);
    const float4* s4 = (const float4*)s;
    float sum = 0.f;
    for (int i = threadIdx.x; i < n4; i += 1024) {
        float4 a = xr[i];
        float4 b = s4[i];
        sum += a.x * b.x + a.y * b.y;
        sum += a.z * b.z + a.w * b.w;
    }
    #pragma unroll
    for (int off = 32; off > 0; off >>= 1)
        sum += __shfl_down(sum, off, 64);
    __shared__ float red[16];
    int wave = threadIdx.x >> 6;
    int lane = threadIdx.x & 63;
    if (lane == 0) red[wave] = sum;
    __syncthreads();
    if (threadIdx.x < 16) {
        float t = red[threadIdx.x];
        #pragma unroll
        for (int off = 8; off > 0; off >>= 1)
            t += __shfl_down(t, off, 16);
        if (threadIdx.x == 0) latent[blockIdx.x] = t;
    }
}

// ---------------------------------------------------------------------------
// Kernel 3: out[b,v] = sum_c latent[b,c] * W_out[v,c] + b_out[v].
// latent (512 floats) cached in LDS (broadcast reads, no bank conflicts).
// Each thread owns one v (W_out row = 32B, two float4 loads), loops over a
// 16-wide slice of b (grid.y = 4) writing coalesced 4B stores.
// ---------------------------------------------------------------------------
__global__ __launch_bounds__(256) void out_kernel(
    const float* __restrict__ latent, const float* __restrict__ Wout,
    const float* __restrict__ bout, float* __restrict__ out) {
    __shared__ float lat[Bn * Cn];
    for (int i = threadIdx.x; i < Bn * Cn; i += 256)
        lat[i] = latent[i];
    __syncthreads();
    int v = blockIdx.x * 256 + threadIdx.x;
    if (v >= Vn) return;
    const float4* wr = (const float4*)(Wout + (size_t)v * Cn);
    float4 w0 = wr[0];
    float4 w1 = wr[1];
    float bb = bout[v];
    int b0 = blockIdx.y * (Bn / 4);
    #pragma unroll 4
    for (int b = b0; b < b0 + Bn / 4; ++b) {
        const float* lb = &lat[b * Cn];
        float acc = bb;
        acc += lb[0] * w0.x + lb[1] * w0.y + lb[2] * w0.z + lb[3] * w0.w;
        acc += lb[4] * w1.x + lb[5] * w1.y + lb[6] * w1.z + lb[7] * w1.w;
        out[(size_t)b * Vn + v] = acc;
    }
}

extern "C" void kernel_launch(void* const* d_in, const int* in_sizes, int n_in,
                              void* d_out, int out_size, void* d_ws, size_t ws_size,
                              hipStream_t stream) {
    const float* x     = (const float*)d_in[0];   // [B,C,V]
    const float* Wctx  = (const float*)d_in[1];   // [V,H]
    const float* Wout  = (const float*)d_in[2];   // [V,C]
    const float* bout  = (const float*)d_in[3];   // [V]
    float*       out   = (float*)d_out;           // [B,V]

    float* s      = (float*)d_ws;                 // [V]
    float* latent = s + Vn;                       // [B*C]

    // K1: rowsum of W_ctx -> s.  4 rows per 256-thread block.
    {
        int waves_total = Vn;
        int blocks = (waves_total * 64 + 255) / 256;  // 12500
        rowsum_kernel<<<blocks, 256, 0, stream>>>(Wctx, s);
    }
    // K2: per-(b,c) dot over V -> latent.
    dot_kernel<<<Bn * Cn, 1024, 0, stream>>>(x, s, latent);
    // K3: tiny GEMM epilogue -> out.
    {
        dim3 grid((Vn + 255) / 256, 4);  // 196 x 4 = 784 blocks
        out_kernel<<<grid, 256, 0, stream>>>(latent, Wout, bout, out);
    }
}

// Round 2
// 181.982 us; speedup vs baseline: 1.0356x; 1.0356x over previous
//
#include <hip/hip_runtime.h>
#include <hip/hip_bf16.h>

// Problem constants (fixed by the reference: B=64, C=8, V=50000, H=128)
constexpr int Bn = 64;
constexpr int Cn = 8;
constexpr int Vn = 50000;
constexpr int Hn = 128;

// ---------------------------------------------------------------------------
// Kernel 1: s[v] = sum_h W_ctx[v,h].
// 256 threads/block, each thread loads TWO float4s (16 B/lane sweet spot).
// Block covers 2048 floats = 16 rows. Row = contiguous 32-thread group;
// width-32 shuffle reduce. 3125 blocks.
// ---------------------------------------------------------------------------
__global__ __launch_bounds__(256) void rowsum_kernel(
    const float* __restrict__ Wctx, float* __restrict__ s) {
    const float4* W4 = (const float4*)Wctx;
    int base = blockIdx.x * 512;      // float4 index of block start
    int t = threadIdx.x;
    float4 a = W4[base + t];          // rows blockIdx*16 + [0,8)
    float4 b = W4[base + 256 + t];    // rows blockIdx*16 + [8,16)
    float sa = a.x + a.y + a.z + a.w;
    float sb = b.x + b.y + b.z + b.w;
    #pragma unroll
    for (int off = 16; off > 0; off >>= 1) {
        sa += __shfl_down(sa, off, 32);
        sb += __shfl_down(sb, off, 32);
    }
    if ((t & 31) == 0) {
        int rowA = blockIdx.x * 16 + (t >> 5);   // (t/32) in [0,8)
        s[rowA]     = sa;
        s[rowA + 8] = sb;
    }
}

// ---------------------------------------------------------------------------
// Kernel 2: latent[r] = dot(x[r,:], s[:]) for r in [0, B*C).
// One 512-thread block per row. Unroll-by-4 float4 loads -> 8 x 16B loads in
// flight per thread; 512 blocks = 2 blocks/CU = 16 waves/CU.
// V/4 = 12500 = 6*4*512 + 212 (tail).
// ---------------------------------------------------------------------------
__global__ __launch_bounds__(512, 4) void dot_kernel(
    const float* __restrict__ x, const float* __restrict__ s,
    float* __restrict__ latent) {
    const float4* xr = (const float4*)(x + (size_t)blockIdx.x * Vn);
    const float4* s4 = (const float4*)s;
    int tid = threadIdx.x;
    float sum = 0.f;
    #pragma unroll 2
    for (int u = 0; u < 6; ++u) {
        int i0 = tid + u * 2048;
        float4 a0 = xr[i0];        float4 b0 = s4[i0];
        float4 a1 = xr[i0 + 512];  float4 b1 = s4[i0 + 512];
        float4 a2 = xr[i0 + 1024]; float4 b2 = s4[i0 + 1024];
        float4 a3 = xr[i0 + 1536]; float4 b3 = s4[i0 + 1536];
        sum += a0.x*b0.x + a0.y*b0.y + a0.z*b0.z + a0.w*b0.w;
        sum += a1.x*b1.x + a1.y*b1.y + a1.z*b1.z + a1.w*b1.w;
        sum += a2.x*b2.x + a2.y*b2.y + a2.z*b2.z + a2.w*b2.w;
        sum += a3.x*b3.x + a3.y*b3.y + a3.z*b3.z + a3.w*b3.w;
    }
    if (tid < 212) {               // tail: indices 12288..12499
        int i = tid + 12288;
        float4 a = xr[i]; float4 b = s4[i];
        sum += a.x*b.x + a.y*b.y + a.z*b.z + a.w*b.w;
    }
    #pragma unroll
    for (int off = 32; off > 0; off >>= 1)
        sum += __shfl_down(sum, off, 64);
    __shared__ float red[8];
    int wave = tid >> 6, lane = tid & 63;
    if (lane == 0) red[wave] = sum;
    __syncthreads();
    if (tid < 8) {
        float tv = red[tid];
        #pragma unroll
        for (int off = 4; off > 0; off >>= 1)
            tv += __shfl_down(tv, off, 8);
        if (tid == 0) latent[blockIdx.x] = tv;
    }
}

// ---------------------------------------------------------------------------
// Kernel 3: out[b,v] = sum_c latent[b,c]*W_out[v,c] + b_out[v].
// Each thread owns 4 consecutive v (float4 stores). latent in LDS (broadcast
// reads). grid = (ceil(12500/256), 4): each y-slice covers 16 b values.
// ---------------------------------------------------------------------------
__global__ __launch_bounds__(256) void out_kernel(
    const float* __restrict__ latent, const float* __restrict__ Wout,
    const float* __restrict__ bout, float* __restrict__ out) {
    __shared__ float lat[Bn * Cn];
    for (int i = threadIdx.x; i < Bn * Cn; i += 256)
        lat[i] = latent[i];
    __syncthreads();
    int vq = blockIdx.x * 256 + threadIdx.x;   // quad-of-v index
    if (vq * 4 >= Vn) return;
    const float4* wr = (const float4*)(Wout + (size_t)vq * 4 * Cn); // 8 f4 = rows v..v+3
    float4 w[8];
    #pragma unroll
    for (int j = 0; j < 8; ++j) w[j] = wr[j];
    float4 bb = ((const float4*)bout)[vq];
    int b0 = blockIdx.y * 16;
    for (int b = b0; b < b0 + 16; ++b) {
        const float* lb = &lat[b * Cn];
        float4 o;
        o.x = bb.x + lb[0]*w[0].x + lb[1]*w[0].y + lb[2]*w[0].z + lb[3]*w[0].w
                   + lb[4]*w[1].x + lb[5]*w[1].y + lb[6]*w[1].z + lb[7]*w[1].w;
        o.y = bb.y + lb[0]*w[2].x + lb[1]*w[2].y + lb[2]*w[2].z + lb[3]*w[2].w
                   + lb[4]*w[3].x + lb[5]*w[3].y + lb[6]*w[3].z + lb[7]*w[3].w;
        o.z = bb.z + lb[0]*w[4].x + lb[1]*w[4].y + lb[2]*w[4].z + lb[3]*w[4].w
                   + lb[4]*w[5].x + lb[5]*w[5].y + lb[6]*w[5].z + lb[7]*w[5].w;
        o.w = bb.w + lb[0]*w[6].x + lb[1]*w[6].y + lb[2]*w[6].z + lb[3]*w[6].w
                   + lb[4]*w[7].x + lb[5]*w[7].y + lb[6]*w[7].z + lb[7]*w[7].w;
        ((float4*)(out + (size_t)b * Vn))[vq] = o;
    }
}

extern "C" void kernel_launch(void* const* d_in, const int* in_sizes, int n_in,
                              void* d_out, int out_size, void* d_ws, size_t ws_size,
                              hipStream_t stream) {
    const float* x    = (const float*)d_in[0];   // [B,C,V]
    const float* Wctx = (const float*)d_in[1];   // [V,H]
    const float* Wout = (const float*)d_in[2];   // [V,C]
    const float* bout = (const float*)d_in[3];   // [V]
    float*       out  = (float*)d_out;           // [B,V]

    float* s      = (float*)d_ws;                // [V]
    float* latent = s + Vn;                      // [B*C]

    rowsum_kernel<<<Vn / 16, 256, 0, stream>>>(Wctx, s);          // 3125 blocks
    dot_kernel<<<Bn * Cn, 512, 0, stream>>>(x, s, latent);        // 512 blocks
    dim3 grid3((Vn / 4 + 255) / 256, 4);                          // 49 x 4
    out_kernel<<<grid3, 256, 0, stream>>>(latent, Wout, bout, out);
}